// Round 7
// baseline (563.867 us; speedup 1.0000x reference)
//
#include <hip/hip_runtime.h>
#include <hip/hip_bf16.h>
#include <math.h>

// Problem constants
#define S 768
#define E 512
#define H 8
#define DK 64
#define TOPK 384
#define NBLOCKS 448

typedef short bf16x8 __attribute__((ext_vector_type(8)));
typedef float f32x4 __attribute__((ext_vector_type(4)));

// ---------------------------------------------------------------------------
// fp32 <-> bf16 split helpers (round-to-nearest-even)
// ---------------------------------------------------------------------------
__device__ __forceinline__ unsigned short f2bf(float x) {
  unsigned u = __float_as_uint(x);
  unsigned r = u + 0x7FFFu + ((u >> 16) & 1u);
  return (unsigned short)(r >> 16);
}
__device__ __forceinline__ float bf2f(unsigned short h) {
  return __uint_as_float(((unsigned)h) << 16);
}
__device__ __forceinline__ void split1(float x, unsigned short& h, unsigned short& l) {
  h = f2bf(x);
  l = f2bf(x - bf2f(h));
}

__device__ __forceinline__ void mfma3(f32x4& d, bf16x8 ah, bf16x8 al,
                                      bf16x8 bh, bf16x8 bl) {
  d = __builtin_amdgcn_mfma_f32_16x16x32_bf16(ah, bh, d, 0, 0, 0);
  d = __builtin_amdgcn_mfma_f32_16x16x32_bf16(ah, bl, d, 0, 0, 0);
  d = __builtin_amdgcn_mfma_f32_16x16x32_bf16(al, bh, d, 0, 0, 0);
}
__device__ __forceinline__ void mfma2(f32x4& d, bf16x8 ah, bf16x8 al, bf16x8 bh) {
  d = __builtin_amdgcn_mfma_f32_16x16x32_bf16(ah, bh, d, 0, 0, 0);
  d = __builtin_amdgcn_mfma_f32_16x16x32_bf16(al, bh, d, 0, 0, 0);
}

__device__ __forceinline__ bf16x8 ldfrag(const unsigned short* p) {
  return *reinterpret_cast<const bf16x8*>(p);
}

// ---------------------------------------------------------------------------
// Software grid barrier: bar[0]=arrival counter, bar[1]=generation.
// AGENT-scope atomics + threadfence (gfx950 per-XCD L2s are non-coherent).
// Timeout valve: a broken barrier gives a wrong answer, never a hang.
// ---------------------------------------------------------------------------
__device__ __forceinline__ void gbar(unsigned* bar) {
  __syncthreads();
  if (threadIdx.x == 0) {
    __threadfence();   // release: drain this block's writes to device scope
    const unsigned gen =
        __hip_atomic_load(bar + 1, __ATOMIC_RELAXED, __HIP_MEMORY_SCOPE_AGENT);
    const unsigned prev =
        __hip_atomic_fetch_add(bar, 1u, __ATOMIC_ACQ_REL, __HIP_MEMORY_SCOPE_AGENT);
    if (prev + 1u == (unsigned)NBLOCKS) {
      __hip_atomic_store(bar, 0u, __ATOMIC_RELAXED, __HIP_MEMORY_SCOPE_AGENT);
      __hip_atomic_fetch_add(bar + 1, 1u, __ATOMIC_RELEASE,
                             __HIP_MEMORY_SCOPE_AGENT);
    } else {
      unsigned spins = 0;
      while (__hip_atomic_load(bar + 1, __ATOMIC_ACQUIRE,
                               __HIP_MEMORY_SCOPE_AGENT) == gen) {
        __builtin_amdgcn_s_sleep(2);
        if (++spins > 40000000u) break;   // safety valve
      }
    }
    __threadfence();   // acquire: invalidate stale cached lines
  }
  __syncthreads();
}

// ---------------------------------------------------------------------------
// Argument bundles
// ---------------------------------------------------------------------------
struct PrepTab {
  const float* src[8];
  unsigned short* hi[8];
  unsigned short* lo[8];
};
struct ProjTab {
  const unsigned short* whi[6];
  const unsigned short* wlo[6];
  const float* bias[6];
};
struct MegaArgs {
  PrepTab prep;
  ProjTab pt;
  unsigned short *Xhi, *Xlo;
  unsigned short *Qhi, *Qlo, *Khi, *Klo, *VThi, *QIhi, *QIlo, *KIhi, *KIlo;
  float *WI, *ISC;
  unsigned* Mask;
  float *Sum, *ATTacc;
  const unsigned short* WoThi;
  const float* bo;
  float* out;
  unsigned* Bar;
};

// ---------------------------------------------------------------------------
// Phase 1: prep — 256-thr virtual blocks (two per real block), 2 barriers.
// LDS per half: float ts[32][33] = 4224 B.
// ---------------------------------------------------------------------------
__device__ __forceinline__ void prep_dev(unsigned char* smh, int vb, int tid,
                                         const PrepTab& t) {
  const int x = vb & 15;
  const int y = (vb >> 4) % 24;
  const int seg = vb / 384;              // 0..7 when vb<3072
  bool act = (vb < 3072);
  int cols = 512;
  if (act) {
    const int rows = (seg == 0) ? 768 : 512;
    cols = (seg == 5) ? 64 : ((seg == 6) ? 8 : 512);
    const int tx = (seg == 6) ? 2 : ((cols + 31) >> 5);
    const int ty = rows >> 5;
    act = (x < tx) && (y < ty);
  }
  const int r0 = y * 32, c0 = x * 32;
  const int rl = tid >> 3, c4 = (tid & 7) << 2;
  float (*ts)[33] = (float(*)[33])smh;
  if (act && seg != 0) {
    const float* src = t.src[seg];
    #pragma unroll
    for (int j = 0; j < 4; ++j) {
      int c = c4 + j;
      ts[rl][c] = (c0 + c < cols) ? src[(size_t)(r0 + rl) * cols + c0 + c] : 0.0f;
    }
  }
  __syncthreads();
  if (act) {
    if (seg == 0) {
      const float* src = t.src[0];
      float4 v = *(const float4*)(src + (size_t)(r0 + rl) * 512 + c0 + c4);
      unsigned short h[4], l[4];
      split1(v.x, h[0], l[0]); split1(v.y, h[1], l[1]);
      split1(v.z, h[2], l[2]); split1(v.w, h[3], l[3]);
      size_t off = (size_t)(r0 + rl) * 512 + c0 + c4;
      *(ushort4*)(t.hi[0] + off) = make_ushort4(h[0], h[1], h[2], h[3]);
      *(ushort4*)(t.lo[0] + off) = make_ushort4(l[0], l[1], l[2], l[3]);
    } else {
      float v0 = ts[c4 + 0][rl], v1 = ts[c4 + 1][rl];
      float v2 = ts[c4 + 2][rl], v3 = ts[c4 + 3][rl];
      unsigned short h[4], l[4];
      split1(v0, h[0], l[0]); split1(v1, h[1], l[1]);
      split1(v2, h[2], l[2]); split1(v3, h[3], l[3]);
      size_t off = (size_t)(c0 + rl) * 512 + r0 + c4;
      *(ushort4*)(t.hi[seg] + off) = make_ushort4(h[0], h[1], h[2], h[3]);
      *(ushort4*)(t.lo[seg] + off) = make_ushort4(l[0], l[1], l[2], l[3]);
    }
  }
  __syncthreads();   // ts reusable next iteration
}

// ---------------------------------------------------------------------------
// Phase 2: proj — 512-thr virtual block = one 64x64 tile. 8 waves of 32x16.
// LDS: Ah/Al/Bh/Bl[64][72] = 36864 B.
// ---------------------------------------------------------------------------
__device__ __forceinline__ void proj_dev(unsigned char* smb, int vb,
                                         const MegaArgs& a) {
  unsigned short (*Ah)[72] = (unsigned short(*)[72])(smb);
  unsigned short (*Al)[72] = (unsigned short(*)[72])(smb + 9216);
  unsigned short (*Bh)[72] = (unsigned short(*)[72])(smb + 18432);
  unsigned short (*Bl)[72] = (unsigned short(*)[72])(smb + 27648);
  const bool act = (vb < 408);
  const int bx = act ? (vb % 34) : 0;
  const int m0 = act ? (vb / 34) * 64 : 0;
  int seg, nt;
  if (bx < 32) { seg = bx >> 3; nt = bx & 7; }
  else         { seg = 4 + (bx - 32); nt = 0; }
  const int n0 = nt * 64;
  const int tid = threadIdx.x;
  const int lane = tid & 63;
  const int wave = tid >> 6;           // 0..7
  const int mq = (wave >> 2) << 5;     // 0 or 32
  const int nq = (wave & 3) << 4;      // 0,16,32,48
  const int l15 = lane & 15;
  const int q8 = (lane >> 4) << 3;
  const int q4 = (lane >> 4) << 2;
  const unsigned short* Whi = a.pt.whi[seg];
  const unsigned short* Wlo = a.pt.wlo[seg];
  const int mm = tid >> 3, kc = (tid & 7) << 3;
  const size_t ga = (size_t)(m0 + mm) * 512 + kc;
  const size_t gb = (size_t)(n0 + mm) * 512 + kc;

  bf16x8 rah, ral, rbh, rbl;
  if (act) {
    rah = ldfrag(a.Xhi + ga); ral = ldfrag(a.Xlo + ga);
    rbh = ldfrag(Whi + gb);   rbl = ldfrag(Wlo + gb);
  }
  f32x4 acc[2] = {};
  for (int cc = 0; cc < 8; ++cc) {
    if (act) {
      *(bf16x8*)&Ah[mm][kc] = rah;  *(bf16x8*)&Al[mm][kc] = ral;
      *(bf16x8*)&Bh[mm][kc] = rbh;  *(bf16x8*)&Bl[mm][kc] = rbl;
      if (cc < 7) {
        const size_t o = (size_t)(cc + 1) << 6;
        rah = ldfrag(a.Xhi + ga + o); ral = ldfrag(a.Xlo + ga + o);
        rbh = ldfrag(Whi + gb + o);   rbl = ldfrag(Wlo + gb + o);
      }
    }
    __syncthreads();
    if (act) {
      #pragma unroll
      for (int ki = 0; ki < 64; ki += 32) {
        const int kk = ki + q8;
        bf16x8 ah0 = *(const bf16x8*)&Ah[mq + l15][kk];
        bf16x8 al0 = *(const bf16x8*)&Al[mq + l15][kk];
        bf16x8 ah1 = *(const bf16x8*)&Ah[mq + 16 + l15][kk];
        bf16x8 al1 = *(const bf16x8*)&Al[mq + 16 + l15][kk];
        bf16x8 bh = *(const bf16x8*)&Bh[nq + l15][kk];
        bf16x8 bl = *(const bf16x8*)&Bl[nq + l15][kk];
        mfma3(acc[0], ah0, al0, bh, bl);
        mfma3(acc[1], ah1, al1, bh, bl);
      }
    }
    __syncthreads();
  }
  if (act) {
    const float* bias = a.pt.bias[seg];
    const int nloc = n0 + nq + l15;
    const float bv = (seg == 5 && nloc >= 8) ? 0.0f : bias[nloc];
    #pragma unroll
    for (int mt = 0; mt < 2; ++mt) {
      #pragma unroll
      for (int r = 0; r < 4; ++r) {
        const int m = m0 + mq + mt * 16 + q4 + r;
        const float v = acc[mt][r] + bv;
        unsigned short h16, l16;
        if (seg == 0) {
          split1(v, h16, l16);
          a.Qhi[(size_t)m * 512 + nloc] = h16;
          a.Qlo[(size_t)m * 512 + nloc] = l16;
        } else if (seg == 1) {
          const int hh = nloc >> 6, dd = nloc & 63;
          split1(v, h16, l16);
          a.Khi[((size_t)hh * S + m) * 64 + dd] = h16;
          a.Klo[((size_t)hh * S + m) * 64 + dd] = l16;
        } else if (seg == 2) {
          a.VThi[((size_t)(nloc >> 6) * 64 + (nloc & 63)) * S + m] = f2bf(v);
        } else if (seg == 3) {
          split1(v, h16, l16);
          a.QIhi[(size_t)m * 512 + nloc] = h16;
          a.QIlo[(size_t)m * 512 + nloc] = l16;
        } else if (seg == 4) {
          split1(v, h16, l16);
          a.KIhi[(size_t)m * 64 + nloc] = h16;
          a.KIlo[(size_t)m * 64 + nloc] = l16;
        } else {
          if (nloc < 8) a.WI[(size_t)m * 8 + nloc] = v;
        }
      }
    }
  }
}

// ---------------------------------------------------------------------------
// Phase 3: indexer — 512-thr virtual block = 32 s-rows x 64 t-cols.
// 8 waves of 16x16. LDS: Qh/Ql[32][136] + wis = 18432 B.
// ---------------------------------------------------------------------------
__device__ __forceinline__ void indexer_dev(unsigned char* smb, int vb,
                                            const MegaArgs& a) {
  unsigned short (*Qh)[136] = (unsigned short(*)[136])(smb);
  unsigned short (*Ql)[136] = (unsigned short(*)[136])(smb + 8704);
  float (*wis)[8] = (float(*)[8])(smb + 17408);
  const bool act = (vb < 288);
  const int t0 = act ? (vb % 12) * 64 : 0;
  const int s0 = act ? (vb / 12) * 32 : 0;
  const int tid = threadIdx.x;
  const int lane = tid & 63;
  const int wave = tid >> 6;
  const int mq = (wave >> 2) << 4;     // 0 or 16
  const int nqb = (wave & 3) << 4;     // 0,16,32,48
  const int l15 = lane & 15;
  const int q8 = (lane >> 4) << 3;
  const int q4 = (lane >> 4) << 2;
  if (act && tid < 256)
    wis[tid >> 3][tid & 7] = a.WI[(size_t)(s0 + (tid >> 3)) * 8 + (tid & 7)];

  const size_t brow = (size_t)(t0 + nqb + l15) * 64;
  bf16x8 kfh[2], kfl[2];
  if (act) {
    #pragma unroll
    for (int kk = 0; kk < 2; ++kk) {
      kfh[kk] = ldfrag(a.KIhi + brow + kk * 32 + q8);
      kfl[kk] = ldfrag(a.KIlo + brow + kk * 32 + q8);
    }
  }
  const int smm = tid >> 4;
  const int skc = (tid & 15) << 3;
  const size_t qbase = (size_t)(s0 + smm) * 512 + skc;
  bf16x8 rq0, rq1;
  if (act) { rq0 = ldfrag(a.QIhi + qbase); rq1 = ldfrag(a.QIlo + qbase); }

  float accI[4] = {};
  for (int hp = 0; hp < 4; ++hp) {
    __syncthreads();
    if (act) {
      *(bf16x8*)&Qh[smm][skc] = rq0;
      *(bf16x8*)&Ql[smm][skc] = rq1;
      if (hp < 3) {
        const size_t g = qbase + (size_t)(hp + 1) * 128;
        rq0 = ldfrag(a.QIhi + g);
        rq1 = ldfrag(a.QIlo + g);
      }
    }
    __syncthreads();
    if (act) {
      #pragma unroll
      for (int hh = 0; hh < 2; ++hh) {
        const int h = hp * 2 + hh;
        f32x4 d = {};
        #pragma unroll
        for (int kk = 0; kk < 2; ++kk) {
          const int ka = hh * 64 + kk * 32 + q8;
          bf16x8 ah = *(const bf16x8*)&Qh[mq + l15][ka];
          bf16x8 al = *(const bf16x8*)&Ql[mq + l15][ka];
          mfma3(d, ah, al, kfh[kk], kfl[kk]);
        }
        #pragma unroll
        for (int r = 0; r < 4; ++r)
          accI[r] = fmaf(fmaxf(d[r], 0.0f), wis[mq + q4 + r][h], accI[r]);
      }
    }
  }
  if (act) {
    #pragma unroll
    for (int r = 0; r < 4; ++r)
      a.ISC[(size_t)(s0 + mq + q4 + r) * S + t0 + nqb + l15] = accI[r];
  }
}

// ---------------------------------------------------------------------------
// Phase 4: topk — 256-thr virtual block per s-row (two per real block).
// LDS per half 4352 B.
// ---------------------------------------------------------------------------
__device__ __forceinline__ void topk_dev(unsigned char* p, int vb, int tid,
                                         const MegaArgs& a) {
  unsigned* ordv = (unsigned*)p;           // 768 * 4 = 3072
  int* hist = (int*)(p + 3072);            // 256 * 4 = 1024
  int* gsum = (int*)(p + 4096);            // 16 * 4
  int* wtot = (int*)(p + 4160);            // 4 * 4
  unsigned* mw = (unsigned*)(p + 4176);    // 24 * 4
  unsigned* shp = (unsigned*)(p + 4272);
  int* shR = (int*)(p + 4276);
  const bool act = (vb < S);
  const int s = act ? vb : 0;
  if (act) {
    for (int i = tid; i < 768; i += 256) {
      float f = a.ISC[s * 768 + i] + 0.0f;
      unsigned u = __float_as_uint(f);
      ordv[i] = (u & 0x80000000u) ? ~u : (u | 0x80000000u);
    }
    const float4 z4 = {0.0f, 0.0f, 0.0f, 0.0f};
    if (tid < 128) *(float4*)(a.ATTacc + (size_t)s * 512 + tid * 4) = z4;
    if (tid < 24) mw[tid] = 0u;
    if (tid < H) a.Sum[tid * S + s] = 0.0f;
    if (tid == 0) { *shp = 0u; *shR = TOPK; }
  }
  __syncthreads();
  for (int pass = 0; pass < 4; ++pass) {
    const int shift = 24 - pass * 8;
    hist[tid] = 0;
    __syncthreads();
    if (act) {
      const unsigned pm = (pass == 0) ? 0u : (0xFFFFFFFFu << (shift + 8));
      const unsigned pref = *shp;
      for (int i = tid; i < 768; i += 256) {
        unsigned o = ordv[i];
        if ((o & pm) == pref) atomicAdd(&hist[(o >> shift) & 255], 1);
      }
    }
    __syncthreads();
    if (tid < 16) {
      int t = 0;
      #pragma unroll
      for (int k = 0; k < 16; ++k) t += hist[tid * 16 + k];
      gsum[tid] = t;
    }
    __syncthreads();
    if (act && tid == 0) {
      int R = *shR;
      int G = 0;
      int g = 15;
      for (; g > 0; --g) {
        if (G + gsum[g] >= R) break;
        G += gsum[g];
      }
      int b = 15;
      for (; b > 0; --b) {
        int c = hist[g * 16 + b];
        if (G + c >= R) break;
        G += c;
      }
      *shp = *shp | ((unsigned)(g * 16 + b) << shift);
      *shR = R - G;
    }
    __syncthreads();
  }
  const unsigned thr = *shp;
  const int need_eq = *shR;
  const int base = tid * 3;
  unsigned o0 = 0, o1 = 0, o2 = 0;
  int c = 0;
  if (act) {
    o0 = ordv[base]; o1 = ordv[base + 1]; o2 = ordv[base + 2];
    c = (o0 == thr) + (o1 == thr) + (o2 == thr);
  }
  const int lane = tid & 63, wv = tid >> 6;
  int sum = c;
  #pragma unroll
  for (int off = 1; off < 64; off <<= 1) {
    int v = __shfl_up(sum, off);
    if (lane >= off) sum += v;
  }
  if (lane == 63) wtot[wv] = sum;
  __syncthreads();
  if (act) {
    int rank = sum - c;
    if (wv > 0) rank += wtot[0];
    if (wv > 1) rank += wtot[1];
    if (wv > 2) rank += wtot[2];
    if (o0 > thr || (o0 == thr && rank < need_eq))
      atomicOr(&mw[base >> 5], 1u << (base & 31));
    if (o0 == thr) ++rank;
    if (o1 > thr || (o1 == thr && rank < need_eq))
      atomicOr(&mw[(base + 1) >> 5], 1u << ((base + 1) & 31));
    if (o1 == thr) ++rank;
    if (o2 > thr || (o2 == thr && rank < need_eq))
      atomicOr(&mw[(base + 2) >> 5], 1u << ((base + 2) & 31));
  }
  __syncthreads();
  if (act && tid < 24) a.Mask[s * 24 + tid] = mw[tid];
}

// ---------------------------------------------------------------------------
// Phase 5: sattn — R1 design (coalesced reg-prefetch K/V staging, 64-t
// chunks, fp32 atomics). LDS: 47872 B.
// ---------------------------------------------------------------------------
__device__ __forceinline__ void sattn_dev(unsigned char* smb, int vb,
                                          const MegaArgs& a) {
  unsigned short (*Ksh)[72] = (unsigned short(*)[72])(smb);
  unsigned short (*Ksl)[72] = (unsigned short(*)[72])(smb + 9216);
  unsigned short (*Vsh)[72] = (unsigned short(*)[72])(smb + 18432);
  unsigned short (*Pshi)[72] = (unsigned short(*)[72])(smb + 27648);
  unsigned short (*Pslo)[72] = (unsigned short(*)[72])(smb + 36864);
  unsigned (*msk)[6] = (unsigned(*)[6])(smb + 46080);
  float* rsumf = (float*)(smb + 47616);
  const bool act = (vb < 384);
  const int ks = act ? (vb & 3) : 0;
  const int s0 = act ? (((vb >> 2) % 12) * 64) : 0;
  const int h  = act ? (vb / 48) : 0;
  const int tid = threadIdx.x;
  const int lane = tid & 63;
  const int wave = tid >> 6;
  const int l15 = lane & 15;
  const int q8 = (lane >> 4) << 3;
  const int q4 = (lane >> 4) << 2;
  const int mq = (wave >> 1) << 4;
  const int nqq = (wave & 1) << 4;
  const int db = (wave & 1) << 5;

  if (act && tid < 384)
    msk[tid & 63][tid >> 6] =
        a.Mask[(size_t)(s0 + (tid & 63)) * 24 + ks * 6 + (tid >> 6)];
  if (act && tid < 64) rsumf[tid] = 0.0f;

  bf16x8 qh0, ql0, qh1, ql1, rkh, rkl, rv;
  size_t gkbase = 0, gvbase = 0;
  if (act) {
    const size_t qrow = (size_t)(s0 + mq + l15) * 512 + h * 64;
    qh0 = ldfrag(a.Qhi + qrow + q8);
    ql0 = ldfrag(a.Qlo + qrow + q8);
    qh1 = ldfrag(a.Qhi + qrow + 32 + q8);
    ql1 = ldfrag(a.Qlo + qrow + 32 + q8);
    const int tr = tid >> 3;
    const int kc = (tid & 7) << 3;
    gkbase = ((size_t)h * S + ks * 192 + tr) * 64 + kc;
    gvbase = ((size_t)h * 64 + tr) * S + ks * 192 + kc;
    rkh = ldfrag(a.Khi + gkbase);
    rkl = ldfrag(a.Klo + gkbase);
    rv  = ldfrag(a.VThi + gvbase);
  }
  const int tr = tid >> 3;
  const int kc = (tid & 7) << 3;

  f32x4 oacc[2] = {};
  for (int ct = 0; ct < 3; ++ct) {
    __syncthreads();
    if (act) {
      *(bf16x8*)&Ksh[tr][kc] = rkh;
      *(bf16x8*)&Ksl[tr][kc] = rkl;
      *(bf16x8*)&Vsh[tr][kc] = rv;
      if (ct < 2) {
        rkh = ldfrag(a.Khi + gkbase + (size_t)(ct + 1) * 4096);
        rkl = ldfrag(a.Klo + gkbase + (size_t)(ct + 1) * 4096);
        rv  = ldfrag(a.VThi + gvbase + (size_t)(ct + 1) * 64);
      }
    }
    __syncthreads();
    if (act) {
      float esum[4] = {0.0f, 0.0f, 0.0f, 0.0f};
      #pragma unroll
      for (int cp = 0; cp < 2; ++cp) {
        const int tcol = nqq + cp * 32;
        f32x4 d = {0.0f, 0.0f, 0.0f, 0.0f};
        bf16x8 bh0 = *(const bf16x8*)&Ksh[tcol + l15][q8];
        bf16x8 bl0 = *(const bf16x8*)&Ksl[tcol + l15][q8];
        bf16x8 bh1 = *(const bf16x8*)&Ksh[tcol + l15][32 + q8];
        bf16x8 bl1 = *(const bf16x8*)&Ksl[tcol + l15][32 + q8];
        mfma3(d, qh0, ql0, bh0, bl0);
        mfma3(d, qh1, ql1, bh1, bl1);
        const int tl = ct * 64 + tcol + l15;
        #pragma unroll
        for (int r = 0; r < 4; ++r) {
          const int srow = mq + q4 + r;
          const unsigned w = msk[srow][tl >> 5];
          float e = ((w >> (tl & 31)) & 1u) ? __expf(d[r] * 0.125f) : 0.0f;
          unsigned short h16, l16;
          split1(e, h16, l16);
          Pshi[srow][tcol + l15] = h16;
          Pslo[srow][tcol + l15] = l16;
          esum[r] += e;
        }
      }
      float v0 = esum[0], v1 = esum[1], v2 = esum[2], v3 = esum[3];
      #pragma unroll
      for (int off = 1; off < 16; off <<= 1) {
        v0 += __shfl_xor(v0, off);
        v1 += __shfl_xor(v1, off);
        v2 += __shfl_xor(v2, off);
        v3 += __shfl_xor(v3, off);
      }
      if (l15 == 0) {
        atomicAdd(&rsumf[mq + q4 + 0], v0);
        atomicAdd(&rsumf[mq + q4 + 1], v1);
        atomicAdd(&rsumf[mq + q4 + 2], v2);
        atomicAdd(&rsumf[mq + q4 + 3], v3);
      }
    }
    __syncthreads();
    if (act) {
      #pragma unroll
      for (int kk = 0; kk < 64; kk += 32) {
        bf16x8 pah = *(const bf16x8*)&Pshi[mq + l15][kk + q8];
        bf16x8 pal = *(const bf16x8*)&Pslo[mq + l15][kk + q8];
        #pragma unroll
        for (int dt = 0; dt < 2; ++dt) {
          bf16x8 vbh = *(const bf16x8*)&Vsh[db + dt * 16 + l15][kk + q8];
          mfma2(oacc[dt], pah, pal, vbh);
        }
      }
    }
  }
  if (act) {
    #pragma unroll
    for (int dt = 0; dt < 2; ++dt) {
      const int dd = db + dt * 16 + l15;
      #pragma unroll
      for (int r = 0; r < 4; ++r) {
        const int s = s0 + mq + q4 + r;
        atomicAdd(&a.ATTacc[(size_t)s * E + h * DK + dd], oacc[dt][r]);
      }
    }
  }
  __syncthreads();
  if (act && tid < 64) atomicAdd(&a.Sum[(size_t)h * S + s0 + tid], rsumf[tid]);
}

// ---------------------------------------------------------------------------
// Phase 6: out — R1 design. LDS: 37952 B.
// ---------------------------------------------------------------------------
__device__ __forceinline__ void out_dev(unsigned char* smb, int vb,
                                        const MegaArgs& a) {
  float (*AccL)[65] = (float(*)[65])(smb);
  float (*ivs)[8] = (float(*)[8])(smb + 4160);
  unsigned short (*Ahi)[520] = (unsigned short(*)[520])(smb + 4672);
  unsigned short (*Alo)[520] = (unsigned short(*)[520])(smb + 21312);
  const bool act = (vb < 384);
  const int tid512 = threadIdx.x;
  const int wave8 = tid512 >> 6;
  const int z = wave8 >> 2;
  const int wave = wave8 & 3;
  const int lane = tid512 & 63;
  const int m0 = act ? (vb / 8) * 16 : 0;
  const int n0 = act ? ((vb % 8) * 64 + wave * 16) : 0;
  const int l15 = lane & 15;
  const int q8 = (lane >> 4) << 3;
  const int q4 = (lane >> 4) << 2;
  if (act && tid512 < 128) {
    const int r = tid512 >> 3, hh = tid512 & 7;
    ivs[r][hh] = 1.0f / a.Sum[(size_t)hh * S + m0 + r];
  }
  __syncthreads();
  if (act) {
    const int row = tid512 >> 5;
    const int kb = (tid512 & 31) << 4;
    const float inv = ivs[row][kb >> 6];
    const float* src = a.ATTacc + (size_t)(m0 + row) * 512 + kb;
    float4 a0 = *(const float4*)(src);
    float4 a1 = *(const float4*)(src + 4);
    float4 a2 = *(const float4*)(src + 8);
    float4 a3 = *(const float4*)(src + 12);
    float v[16] = {a0.x, a0.y, a0.z, a0.w, a1.x, a1.y, a1.z, a1.w,
                   a2.x, a2.y, a2.z, a2.w, a3.x, a3.y, a3.z, a3.w};
    #pragma unroll
    for (int i = 0; i < 16; ++i) {
      unsigned short hh, ll;
      split1(v[i] * inv, hh, ll);
      Ahi[row][kb + i] = hh;
      Alo[row][kb + i] = ll;
    }
  }
  __syncthreads();
  f32x4 acc = {};
  if (act) {
    const size_t brow = (size_t)(n0 + l15) * 512;
    #pragma unroll
    for (int it = 0; it < 8; ++it) {
      const int ko = (z << 8) + (it << 5) + q8;
      bf16x8 ah = *(const bf16x8*)&Ahi[l15][ko];
      bf16x8 al = *(const bf16x8*)&Alo[l15][ko];
      bf16x8 bh = ldfrag(a.WoThi + brow + ko);
      mfma2(acc, ah, al, bh);
    }
    if (z == 1) {
      #pragma unroll
      for (int r = 0; r < 4; ++r)
        AccL[q4 + r][wave * 16 + l15] = acc[r];
    }
  }
  __syncthreads();
  if (act && z == 0) {
    const int n = n0 + l15;
    const float bv = a.bo[n];
    #pragma unroll
    for (int r = 0; r < 4; ++r)
      a.out[(size_t)(m0 + q4 + r) * 512 + n] =
          acc[r] + AccL[q4 + r][wave * 16 + l15] + bv;
  }
}

// ---------------------------------------------------------------------------
// Persistent mega-kernel: 448 blocks x 512 threads; 2 blocks/CU guaranteed
// (VGPR<=128 via launch_bounds, LDS 47872 B) -> all blocks resident ->
// software grid barrier is deadlock-safe.
// ---------------------------------------------------------------------------
__global__ __launch_bounds__(512, 4) void mega_kernel(MegaArgs a) {
  __shared__ __align__(16) unsigned char sm[47872];
  const int bid = blockIdx.x;
  const int tid = threadIdx.x;
  const int half = tid >> 8;
  const int t256 = tid & 255;
  const int slot = (bid << 1) + half;
  const int nslots = NBLOCKS * 2;

  // phase 1: prep (4 iterations over 3072 virtual 256-thr blocks)
  for (int it = 0; it < 4; ++it)
    prep_dev(sm + half * 4224, it * nslots + slot, t256, a.prep);
  gbar(a.Bar);
  // phase 2: projections (408 virtual 512-thr tiles)
  proj_dev(sm, bid, a);
  gbar(a.Bar);
  // phase 3: indexer (288 virtual 512-thr tiles)
  indexer_dev(sm, bid, a);
  gbar(a.Bar);
  // phase 4: top-k (768 virtual 256-thr rows)
  topk_dev(sm + half * 4352, slot, t256, a);
  gbar(a.Bar);
  // phase 5: sparse attention (384 virtual 512-thr blocks)
  sattn_dev(sm, bid, a);
  gbar(a.Bar);
  // phase 6: output projection (384 virtual 512-thr blocks)
  out_dev(sm, bid, a);
}

// ---------------------------------------------------------------------------
// Launch
// ---------------------------------------------------------------------------
extern "C" void kernel_launch(void* const* d_in, const int* in_sizes, int n_in,
                              void* d_out, int out_size, void* d_ws, size_t ws_size,
                              hipStream_t stream) {
  const float* x    = (const float*)d_in[0];
  const float* Wq   = (const float*)d_in[1];
  const float* bq   = (const float*)d_in[2];
  const float* Wk   = (const float*)d_in[3];
  const float* bk   = (const float*)d_in[4];
  const float* Wv   = (const float*)d_in[5];
  const float* bv   = (const float*)d_in[6];
  const float* Wo   = (const float*)d_in[7];
  const float* bo   = (const float*)d_in[8];
  const float* iqW  = (const float*)d_in[9];
  const float* iqb  = (const float*)d_in[10];
  const float* ikW  = (const float*)d_in[11];
  const float* ikb  = (const float*)d_in[12];
  const float* wpW  = (const float*)d_in[13];
  const float* wpb  = (const float*)d_in[14];

  float* ws = (float*)d_ws;
  float* WI   = ws;                         // S*H fp32
  float* ISC  = WI + S * H;                 // S*S fp32
  unsigned* Mask = (unsigned*)(ISC + S * S);  // S*24
  float* Sum  = (float*)(Mask + S * 24);    // H*S
  float* ATTacc = Sum + H * S;              // S*E fp32 (atomic accumulator)
  unsigned short* u = (unsigned short*)(ATTacc + S * E);
  unsigned short* Xhi  = u;             u += S * E;
  unsigned short* Xlo  = u;             u += S * E;
  unsigned short* Qhi  = u;             u += S * E;
  unsigned short* Qlo  = u;             u += S * E;
  unsigned short* Khi  = u;             u += S * E;
  unsigned short* Klo  = u;             u += S * E;
  unsigned short* VThi = u;             u += S * E;
  unsigned short* QIhi = u;             u += S * E;
  unsigned short* QIlo = u;             u += S * E;
  unsigned short* KIhi = u;             u += S * DK;
  unsigned short* KIlo = u;             u += S * DK;
  unsigned short* WTq_hi = u;           u += E * E;
  unsigned short* WTk_hi = u;           u += E * E;
  unsigned short* WTv_hi = u;           u += E * E;
  unsigned short* WTiq_hi = u;          u += E * E;
  unsigned short* WTik_hi = u;          u += 64 * E;
  unsigned short* WTwp_hi = u;          u += 64 * E;
  unsigned short* WTo_hi = u;           u += E * E;
  unsigned short* WTq_lo = u;           u += E * E;
  unsigned short* WTk_lo = u;           u += E * E;
  unsigned short* WTv_lo = u;           u += E * E;
  unsigned short* WTiq_lo = u;          u += E * E;
  unsigned short* WTik_lo = u;          u += 64 * E;
  unsigned short* WTwp_lo = u;          u += 64 * E;
  unsigned short* WTo_lo = u;           u += E * E;
  unsigned* Bar = (unsigned*)u;         // 2 x u32 barrier cells

  MegaArgs ma;
  ma.prep.src[0] = x;    ma.prep.hi[0] = Xhi;     ma.prep.lo[0] = Xlo;
  ma.prep.src[1] = Wq;   ma.prep.hi[1] = WTq_hi;  ma.prep.lo[1] = WTq_lo;
  ma.prep.src[2] = Wk;   ma.prep.hi[2] = WTk_hi;  ma.prep.lo[2] = WTk_lo;
  ma.prep.src[3] = Wv;   ma.prep.hi[3] = WTv_hi;  ma.prep.lo[3] = WTv_lo;
  ma.prep.src[4] = iqW;  ma.prep.hi[4] = WTiq_hi; ma.prep.lo[4] = WTiq_lo;
  ma.prep.src[5] = ikW;  ma.prep.hi[5] = WTik_hi; ma.prep.lo[5] = WTik_lo;
  ma.prep.src[6] = wpW;  ma.prep.hi[6] = WTwp_hi; ma.prep.lo[6] = WTwp_lo;
  ma.prep.src[7] = Wo;   ma.prep.hi[7] = WTo_hi;  ma.prep.lo[7] = WTo_lo;

  ma.pt.whi[0] = WTq_hi;  ma.pt.wlo[0] = WTq_lo;  ma.pt.bias[0] = bq;
  ma.pt.whi[1] = WTk_hi;  ma.pt.wlo[1] = WTk_lo;  ma.pt.bias[1] = bk;
  ma.pt.whi[2] = WTv_hi;  ma.pt.wlo[2] = WTv_lo;  ma.pt.bias[2] = bv;
  ma.pt.whi[3] = WTiq_hi; ma.pt.wlo[3] = WTiq_lo; ma.pt.bias[3] = iqb;
  ma.pt.whi[4] = WTik_hi; ma.pt.wlo[4] = WTik_lo; ma.pt.bias[4] = ikb;
  ma.pt.whi[5] = WTwp_hi; ma.pt.wlo[5] = WTwp_lo; ma.pt.bias[5] = wpb;

  ma.Xhi = Xhi;   ma.Xlo = Xlo;
  ma.Qhi = Qhi;   ma.Qlo = Qlo;
  ma.Khi = Khi;   ma.Klo = Klo;
  ma.VThi = VThi;
  ma.QIhi = QIhi; ma.QIlo = QIlo;
  ma.KIhi = KIhi; ma.KIlo = KIlo;
  ma.WI = WI;     ma.ISC = ISC;
  ma.Mask = Mask;
  ma.Sum = Sum;   ma.ATTacc = ATTacc;
  ma.WoThi = WTo_hi;
  ma.bo = bo;
  ma.out = (float*)d_out;
  ma.Bar = Bar;

  hipMemsetAsync(Bar, 0, 2 * sizeof(unsigned), stream);
  mega_kernel<<<dim3(NBLOCKS), dim3(512), 0, stream>>>(ma);
}

// Round 8
// 138.107 us; speedup vs baseline: 4.0828x; 4.0828x over previous
//
#include <hip/hip_runtime.h>
#include <hip/hip_bf16.h>
#include <math.h>

// Problem constants
#define S 768
#define E 512
#define H 8
#define DK 64
#define TOPK 384

typedef short bf16x8 __attribute__((ext_vector_type(8)));
typedef float f32x4 __attribute__((ext_vector_type(4)));

// ---------------------------------------------------------------------------
// fp32 <-> bf16 split helpers (round-to-nearest-even)
// ---------------------------------------------------------------------------
__device__ __forceinline__ unsigned short f2bf(float x) {
  unsigned u = __float_as_uint(x);
  unsigned r = u + 0x7FFFu + ((u >> 16) & 1u);
  return (unsigned short)(r >> 16);
}
__device__ __forceinline__ float bf2f(unsigned short h) {
  return __uint_as_float(((unsigned)h) << 16);
}
__device__ __forceinline__ void split1(float x, unsigned short& h, unsigned short& l) {
  h = f2bf(x);
  l = f2bf(x - bf2f(h));
}

// 3-term fp32-accurate bf16 MFMA
__device__ __forceinline__ void mfma3(f32x4& d, bf16x8 ah, bf16x8 al,
                                      bf16x8 bh, bf16x8 bl) {
  d = __builtin_amdgcn_mfma_f32_16x16x32_bf16(ah, bh, d, 0, 0, 0);
  d = __builtin_amdgcn_mfma_f32_16x16x32_bf16(ah, bl, d, 0, 0, 0);
  d = __builtin_amdgcn_mfma_f32_16x16x32_bf16(al, bh, d, 0, 0, 0);
}
// 2-term (B bf16-only)
__device__ __forceinline__ void mfma2(f32x4& d, bf16x8 ah, bf16x8 al, bf16x8 bh) {
  d = __builtin_amdgcn_mfma_f32_16x16x32_bf16(ah, bh, d, 0, 0, 0);
  d = __builtin_amdgcn_mfma_f32_16x16x32_bf16(al, bh, d, 0, 0, 0);
}

__device__ __forceinline__ bf16x8 ldfrag(const unsigned short* p) {
  return *reinterpret_cast<const bf16x8*>(p);
}

// ---------------------------------------------------------------------------
// prep (R1-exact)
// ---------------------------------------------------------------------------
struct PrepTab {
  const float* src[8];
  unsigned short* hi[8];
  unsigned short* lo[8];
};

__global__ __launch_bounds__(256) void prep_kernel(PrepTab t) {
  const int seg = blockIdx.z;
  const int rows = (seg == 0) ? 768 : 512;
  const int cols = (seg == 5) ? 64 : ((seg == 6) ? 8 : 512);
  const int tx = (seg == 6) ? 2 : ((cols + 31) >> 5);
  const int ty = rows >> 5;
  if ((int)blockIdx.x >= tx || (int)blockIdx.y >= ty) return;
  const int r0 = blockIdx.y * 32, c0 = blockIdx.x * 32;
  const int tid = threadIdx.x;
  const int rl = tid >> 3, c4 = (tid & 7) << 2;
  const float* src = t.src[seg];
  if (seg == 0) {
    float4 v = *(const float4*)(src + (size_t)(r0 + rl) * cols + c0 + c4);
    unsigned short h[4], l[4];
    split1(v.x, h[0], l[0]); split1(v.y, h[1], l[1]);
    split1(v.z, h[2], l[2]); split1(v.w, h[3], l[3]);
    size_t off = (size_t)(r0 + rl) * cols + c0 + c4;
    *(ushort4*)(t.hi[seg] + off) = make_ushort4(h[0], h[1], h[2], h[3]);
    *(ushort4*)(t.lo[seg] + off) = make_ushort4(l[0], l[1], l[2], l[3]);
  } else {
    __shared__ float ts[32][33];
    #pragma unroll
    for (int j = 0; j < 4; ++j) {
      int c = c4 + j;
      ts[rl][c] = (c0 + c < cols) ? src[(size_t)(r0 + rl) * cols + c0 + c] : 0.0f;
    }
    __syncthreads();
    float v0 = ts[c4 + 0][rl], v1 = ts[c4 + 1][rl];
    float v2 = ts[c4 + 2][rl], v3 = ts[c4 + 3][rl];
    unsigned short h[4], l[4];
    split1(v0, h[0], l[0]); split1(v1, h[1], l[1]);
    split1(v2, h[2], l[2]); split1(v3, h[3], l[3]);
    size_t off = (size_t)(c0 + rl) * 512 + r0 + c4;
    *(ushort4*)(t.hi[seg] + off) = make_ushort4(h[0], h[1], h[2], h[3]);
    *(ushort4*)(t.lo[seg] + off) = make_ushort4(l[0], l[1], l[2], l[3]);
  }
}

// ---------------------------------------------------------------------------
// Fused projections via MFMA (R1-exact: LDS chunk-staged, reg-prefetch)
// ---------------------------------------------------------------------------
struct ProjTab {
  const unsigned short* whi[6];
  const unsigned short* wlo[6];
  const float* bias[6];
};

__global__ __launch_bounds__(256) void proj_mfma_kernel(
    const unsigned short* __restrict__ Xhi, const unsigned short* __restrict__ Xlo,
    ProjTab pt,
    unsigned short* __restrict__ Qhi, unsigned short* __restrict__ Qlo,
    unsigned short* __restrict__ Khi, unsigned short* __restrict__ Klo,
    unsigned short* __restrict__ VThi,
    unsigned short* __restrict__ QIhi, unsigned short* __restrict__ QIlo,
    unsigned short* __restrict__ KIhi, unsigned short* __restrict__ KIlo,
    float* __restrict__ WI) {
  __shared__ __align__(16) unsigned short Ah[64][72];
  __shared__ __align__(16) unsigned short Al[64][72];
  __shared__ __align__(16) unsigned short Bh[64][72];
  __shared__ __align__(16) unsigned short Bl[64][72];
  const int bx = blockIdx.x;
  int seg, nt;
  if (bx < 32) { seg = bx >> 3; nt = bx & 7; }
  else         { seg = 4 + (bx - 32); nt = 0; }
  const int m0 = blockIdx.y * 64;
  const int n0 = nt * 64;
  const int tid = threadIdx.x;
  const int lane = tid & 63;
  const int wave = tid >> 6;
  const int mq = (wave >> 1) << 5;
  const int nq = (wave & 1) << 5;
  const int l15 = lane & 15;
  const int q8 = (lane >> 4) << 3;
  const int q4 = (lane >> 4) << 2;
  const unsigned short* Whi = pt.whi[seg];
  const unsigned short* Wlo = pt.wlo[seg];

  const int mm0 = tid >> 3,          kc0 = (tid & 7) << 3;
  const int mm1 = (tid + 256) >> 3,  kc1 = ((tid + 256) & 7) << 3;
  const size_t ga0 = (size_t)(m0 + mm0) * 512 + kc0;
  const size_t gb0 = (size_t)(n0 + mm0) * 512 + kc0;
  const size_t ga1 = (size_t)(m0 + mm1) * 512 + kc1;
  const size_t gb1 = (size_t)(n0 + mm1) * 512 + kc1;

  bf16x8 rah0 = ldfrag(Xhi + ga0), ral0 = ldfrag(Xlo + ga0);
  bf16x8 rbh0 = ldfrag(Whi + gb0), rbl0 = ldfrag(Wlo + gb0);
  bf16x8 rah1 = ldfrag(Xhi + ga1), ral1 = ldfrag(Xlo + ga1);
  bf16x8 rbh1 = ldfrag(Whi + gb1), rbl1 = ldfrag(Wlo + gb1);

  f32x4 acc[2][2] = {};
  for (int cc = 0; cc < 8; ++cc) {
    *(bf16x8*)&Ah[mm0][kc0] = rah0;
    *(bf16x8*)&Al[mm0][kc0] = ral0;
    *(bf16x8*)&Bh[mm0][kc0] = rbh0;
    *(bf16x8*)&Bl[mm0][kc0] = rbl0;
    *(bf16x8*)&Ah[mm1][kc1] = rah1;
    *(bf16x8*)&Al[mm1][kc1] = ral1;
    *(bf16x8*)&Bh[mm1][kc1] = rbh1;
    *(bf16x8*)&Bl[mm1][kc1] = rbl1;
    if (cc < 7) {
      const size_t o = (size_t)(cc + 1) << 6;
      rah0 = ldfrag(Xhi + ga0 + o); ral0 = ldfrag(Xlo + ga0 + o);
      rbh0 = ldfrag(Whi + gb0 + o); rbl0 = ldfrag(Wlo + gb0 + o);
      rah1 = ldfrag(Xhi + ga1 + o); ral1 = ldfrag(Xlo + ga1 + o);
      rbh1 = ldfrag(Whi + gb1 + o); rbl1 = ldfrag(Wlo + gb1 + o);
    }
    __syncthreads();
    #pragma unroll
    for (int ki = 0; ki < 64; ki += 32) {
      const int kk = ki + q8;
      bf16x8 ah0 = *(const bf16x8*)&Ah[mq + l15][kk];
      bf16x8 al0 = *(const bf16x8*)&Al[mq + l15][kk];
      bf16x8 ah1 = *(const bf16x8*)&Ah[mq + 16 + l15][kk];
      bf16x8 al1 = *(const bf16x8*)&Al[mq + 16 + l15][kk];
      bf16x8 bh0 = *(const bf16x8*)&Bh[nq + l15][kk];
      bf16x8 bl0 = *(const bf16x8*)&Bl[nq + l15][kk];
      bf16x8 bh1 = *(const bf16x8*)&Bh[nq + 16 + l15][kk];
      bf16x8 bl1 = *(const bf16x8*)&Bl[nq + 16 + l15][kk];
      mfma3(acc[0][0], ah0, al0, bh0, bl0);
      mfma3(acc[0][1], ah0, al0, bh1, bl1);
      mfma3(acc[1][0], ah1, al1, bh0, bl0);
      mfma3(acc[1][1], ah1, al1, bh1, bl1);
    }
    __syncthreads();
  }

  const float* bias = pt.bias[seg];
  #pragma unroll
  for (int ntt = 0; ntt < 2; ++ntt) {
    const int nloc = n0 + nq + ntt * 16 + l15;
    const float bv = (seg == 5 && nloc >= 8) ? 0.0f : bias[nloc];
    #pragma unroll
    for (int mt = 0; mt < 2; ++mt) {
      #pragma unroll
      for (int r = 0; r < 4; ++r) {
        const int m = m0 + mq + mt * 16 + q4 + r;
        const float v = acc[mt][ntt][r] + bv;
        unsigned short h16, l16;
        if (seg == 0) {
          split1(v, h16, l16);
          Qhi[(size_t)m * 512 + nloc] = h16;
          Qlo[(size_t)m * 512 + nloc] = l16;
        } else if (seg == 1) {
          const int hh = nloc >> 6, dd = nloc & 63;
          split1(v, h16, l16);
          Khi[((size_t)hh * S + m) * 64 + dd] = h16;
          Klo[((size_t)hh * S + m) * 64 + dd] = l16;
        } else if (seg == 2) {
          VThi[((size_t)(nloc >> 6) * 64 + (nloc & 63)) * S + m] = f2bf(v);
        } else if (seg == 3) {
          split1(v, h16, l16);
          QIhi[(size_t)m * 512 + nloc] = h16;
          QIlo[(size_t)m * 512 + nloc] = l16;
        } else if (seg == 4) {
          split1(v, h16, l16);
          KIhi[(size_t)m * 64 + nloc] = h16;
          KIlo[(size_t)m * 64 + nloc] = l16;
        } else {
          if (nloc < 8) WI[(size_t)m * 8 + nloc] = v;
        }
      }
    }
  }
}

// ---------------------------------------------------------------------------
// Indexer via MFMA (R1-exact: LDS-staged QI per head-pair, reg-prefetch)
// ---------------------------------------------------------------------------
__global__ __launch_bounds__(256) void indexer_mfma_kernel(
    const unsigned short* __restrict__ QIhi, const unsigned short* __restrict__ QIlo,
    const unsigned short* __restrict__ KIhi, const unsigned short* __restrict__ KIlo,
    const float* __restrict__ WI, float* __restrict__ ISC) {
  __shared__ __align__(16) unsigned short Qh[32][136];
  __shared__ __align__(16) unsigned short Ql[32][136];
  __shared__ float wis[32][8];
  const int s0 = blockIdx.y * 32, t0 = blockIdx.x * 64;
  const int tid = threadIdx.x;
  const int lane = tid & 63;
  const int wave = tid >> 6;
  const int mq = (wave >> 1) << 4;
  const int nqb = (wave & 1) << 5;
  const int l15 = lane & 15;
  const int q8 = (lane >> 4) << 3;
  const int q4 = (lane >> 4) << 2;
  wis[tid >> 3][tid & 7] = WI[(size_t)(s0 + (tid >> 3)) * 8 + (tid & 7)];

  const size_t brow0 = (size_t)(t0 + nqb + l15) * 64;
  const size_t brow1 = (size_t)(t0 + nqb + 16 + l15) * 64;
  bf16x8 kfh[2][2], kfl[2][2];
  #pragma unroll
  for (int kk = 0; kk < 2; ++kk) {
    const int kb = kk * 32 + q8;
    kfh[kk][0] = ldfrag(KIhi + brow0 + kb);
    kfl[kk][0] = ldfrag(KIlo + brow0 + kb);
    kfh[kk][1] = ldfrag(KIhi + brow1 + kb);
    kfl[kk][1] = ldfrag(KIlo + brow1 + kb);
  }

  const int smm = tid >> 3;
  const int skc = (tid & 7) << 4;
  const size_t qbase = (size_t)(s0 + smm) * 512 + skc;
  bf16x8 rq0 = ldfrag(QIhi + qbase);
  bf16x8 rq1 = ldfrag(QIhi + qbase + 8);
  bf16x8 rq2 = ldfrag(QIlo + qbase);
  bf16x8 rq3 = ldfrag(QIlo + qbase + 8);

  float accI[2][4] = {};
  for (int hp = 0; hp < 4; ++hp) {
    __syncthreads();
    *(bf16x8*)&Qh[smm][skc]     = rq0;
    *(bf16x8*)&Qh[smm][skc + 8] = rq1;
    *(bf16x8*)&Ql[smm][skc]     = rq2;
    *(bf16x8*)&Ql[smm][skc + 8] = rq3;
    if (hp < 3) {
      const size_t g = qbase + (size_t)(hp + 1) * 128;
      rq0 = ldfrag(QIhi + g);
      rq1 = ldfrag(QIhi + g + 8);
      rq2 = ldfrag(QIlo + g);
      rq3 = ldfrag(QIlo + g + 8);
    }
    __syncthreads();
    #pragma unroll
    for (int hh = 0; hh < 2; ++hh) {
      const int h = hp * 2 + hh;
      f32x4 d[2] = {};
      #pragma unroll
      for (int kk = 0; kk < 2; ++kk) {
        const int ka = hh * 64 + kk * 32 + q8;
        bf16x8 ah = *(const bf16x8*)&Qh[mq + l15][ka];
        bf16x8 al = *(const bf16x8*)&Ql[mq + l15][ka];
        mfma3(d[0], ah, al, kfh[kk][0], kfl[kk][0]);
        mfma3(d[1], ah, al, kfh[kk][1], kfl[kk][1]);
      }
      #pragma unroll
      for (int r = 0; r < 4; ++r) {
        const float w = wis[mq + q4 + r][h];
        accI[0][r] = fmaf(fmaxf(d[0][r], 0.0f), w, accI[0][r]);
        accI[1][r] = fmaf(fmaxf(d[1][r], 0.0f), w, accI[1][r]);
      }
    }
  }
  #pragma unroll
  for (int ntt = 0; ntt < 2; ++ntt)
    #pragma unroll
    for (int r = 0; r < 4; ++r)
      ISC[(size_t)(s0 + mq + q4 + r) * S + t0 + nqb + ntt * 16 + l15] = accI[ntt][r];
}

// ---------------------------------------------------------------------------
// Top-k via exact radix select; shfl-based scan (2 barriers in scan vs 16);
// zeroes Sum and ATTacc for the downstream atomic accumulation.
// ---------------------------------------------------------------------------
__global__ __launch_bounds__(256) void topk_kernel(
    const float* __restrict__ ISC, unsigned* __restrict__ Mask,
    float* __restrict__ Sum, float* __restrict__ ATTacc) {
  __shared__ unsigned ordv[768];
  __shared__ int hist[256];
  __shared__ int gsum[16];
  __shared__ int wtot[4];
  __shared__ unsigned mw[24];
  __shared__ unsigned sh_prefix;
  __shared__ int sh_R;
  const int s = blockIdx.x;
  const int tid = threadIdx.x;
  for (int i = tid; i < 768; i += 256) {
    float f = ISC[s * 768 + i] + 0.0f;
    unsigned u = __float_as_uint(f);
    ordv[i] = (u & 0x80000000u) ? ~u : (u | 0x80000000u);
  }
  {
    const float4 z4 = {0.0f, 0.0f, 0.0f, 0.0f};
    if (tid < 128) *(float4*)(ATTacc + (size_t)s * 512 + tid * 4) = z4;
  }
  if (tid < 24) mw[tid] = 0u;
  if (tid < H) Sum[tid * S + s] = 0.0f;
  if (tid == 0) { sh_prefix = 0u; sh_R = TOPK; }
  __syncthreads();
  for (int pass = 0; pass < 4; ++pass) {
    const int shift = 24 - pass * 8;
    hist[tid] = 0;
    __syncthreads();
    const unsigned pm = (pass == 0) ? 0u : (0xFFFFFFFFu << (shift + 8));
    const unsigned pref = sh_prefix;
    for (int i = tid; i < 768; i += 256) {
      unsigned o = ordv[i];
      if ((o & pm) == pref) atomicAdd(&hist[(o >> shift) & 255], 1);
    }
    __syncthreads();
    if (tid < 16) {
      int t = 0;
      #pragma unroll
      for (int k = 0; k < 16; ++k) t += hist[tid * 16 + k];
      gsum[tid] = t;
    }
    __syncthreads();
    if (tid == 0) {
      int R = sh_R;
      int G = 0;
      int g = 15;
      for (; g > 0; --g) {
        if (G + gsum[g] >= R) break;
        G += gsum[g];
      }
      int b = 15;
      for (; b > 0; --b) {
        int c = hist[g * 16 + b];
        if (G + c >= R) break;
        G += c;
      }
      sh_prefix = sh_prefix | ((unsigned)(g * 16 + b) << shift);
      sh_R = R - G;
    }
    __syncthreads();
  }
  const unsigned thr = sh_prefix;
  const int need_eq = sh_R;
  const int base = tid * 3;
  unsigned o0 = ordv[base], o1 = ordv[base + 1], o2 = ordv[base + 2];
  int c = (o0 == thr) + (o1 == thr) + (o2 == thr);
  const int lane = tid & 63, wv = tid >> 6;
  int sum = c;
  #pragma unroll
  for (int off = 1; off < 64; off <<= 1) {
    int v = __shfl_up(sum, off);
    if (lane >= off) sum += v;
  }
  if (lane == 63) wtot[wv] = sum;
  __syncthreads();
  int rank = sum - c;
  if (wv > 0) rank += wtot[0];
  if (wv > 1) rank += wtot[1];
  if (wv > 2) rank += wtot[2];
  if (o0 > thr || (o0 == thr && rank < need_eq))
    atomicOr(&mw[base >> 5], 1u << (base & 31));
  if (o0 == thr) ++rank;
  if (o1 > thr || (o1 == thr && rank < need_eq))
    atomicOr(&mw[(base + 1) >> 5], 1u << ((base + 1) & 31));
  if (o1 == thr) ++rank;
  if (o2 > thr || (o2 == thr && rank < need_eq))
    atomicOr(&mw[(base + 2) >> 5], 1u << ((base + 2) & 31));
  __syncthreads();
  if (tid < 24) Mask[s * 24 + tid] = mw[tid];
}

// ---------------------------------------------------------------------------
// Fused masked attention — K LDS-staged (coalesced, reg-prefetched);
// V fragments global->reg (per-wave-private, prefetched 1 chunk ahead);
// P single-buffered. Barrier graph: [C] PV(prev) -> stage K -> [B] -> QK.
// 2 barriers/chunk (7 total vs R1's 10). esum held in regs across chunks.
// LDS: 4*9216 + 1536 + 256 = 38656 B.
// ---------------------------------------------------------------------------
__global__ __launch_bounds__(512) void sattn_kernel(
    const unsigned short* __restrict__ Qhi, const unsigned short* __restrict__ Qlo,
    const unsigned short* __restrict__ Khi, const unsigned short* __restrict__ Klo,
    const unsigned short* __restrict__ VThi,
    const unsigned* __restrict__ Mask, float* __restrict__ ATTacc,
    float* __restrict__ Sum) {
  __shared__ __align__(16) unsigned short Ksh[64][72];
  __shared__ __align__(16) unsigned short Ksl[64][72];
  __shared__ __align__(16) unsigned short Pshi[64][72];
  __shared__ __align__(16) unsigned short Pslo[64][72];
  __shared__ unsigned msk[64][6];
  __shared__ float rsumf[64];
  const int ks = blockIdx.x;
  const int s0 = blockIdx.y * 64;
  const int h  = blockIdx.z;
  const int tid = threadIdx.x;
  const int lane = tid & 63;
  const int wave = tid >> 6;          // 0..7
  const int l15 = lane & 15;
  const int q8 = (lane >> 4) << 3;
  const int q4 = (lane >> 4) << 2;
  const int mq = (wave >> 1) << 4;    // 0,16,32,48
  const int nqq = (wave & 1) << 4;    // 0 or 16 (column-quadrant base)
  const int db = (wave & 1) << 5;     // 0 or 32 (d-half for PV)

  if (tid < 384) msk[tid & 63][tid >> 6] =
      Mask[(size_t)(s0 + (tid & 63)) * 24 + ks * 6 + (tid >> 6)];
  if (tid < 64) rsumf[tid] = 0.0f;

  const size_t qrow = (size_t)(s0 + mq + l15) * 512 + h * 64;
  bf16x8 qh0 = ldfrag(Qhi + qrow + q8);
  bf16x8 ql0 = ldfrag(Qlo + qrow + q8);
  bf16x8 qh1 = ldfrag(Qhi + qrow + 32 + q8);
  bf16x8 ql1 = ldfrag(Qlo + qrow + 32 + q8);

  // K staging slots + chunk-0 preload (coalesced)
  const int tr = tid >> 3;          // 0..63
  const int kc = (tid & 7) << 3;    // 0..56
  const size_t gkbase = ((size_t)h * S + ks * 192 + tr) * 64 + kc;
  bf16x8 rkh = ldfrag(Khi + gkbase);
  bf16x8 rkl = ldfrag(Klo + gkbase);

  // V fragments (per-wave-private): row = h*64 + db + dt*16 + l15,
  // col = ks*192 + ct*64 + kk + q8. Chunk 0 preload; prefetch 1 ahead.
  const size_t vb0 = ((size_t)h * 64 + db + l15) * S + ks * 192 + q8;
  bf16x8 v00 = ldfrag(VThi + vb0);
  bf16x8 v01 = ldfrag(VThi + vb0 + 32);
  bf16x8 v10 = ldfrag(VThi + vb0 + (size_t)16 * S);
  bf16x8 v11 = ldfrag(VThi + vb0 + (size_t)16 * S + 32);

  float esum[4] = {0.0f, 0.0f, 0.0f, 0.0f};
  f32x4 oacc[2] = {};
  for (int ct = 0; ct < 3; ++ct) {
    __syncthreads();   // C: ct=0 -> msk/rsumf ready; ct>0 -> QK(ct-1) done
                       //    reading Ksh AND P(ct-1) fully written
    if (ct > 0) {
      // ---- PV for chunk ct-1: P from LDS, V(ct-1) from regs ----
      #pragma unroll
      for (int kk = 0; kk < 64; kk += 32) {
        bf16x8 pah = *(const bf16x8*)&Pshi[mq + l15][kk + q8];
        bf16x8 pal = *(const bf16x8*)&Pslo[mq + l15][kk + q8];
        mfma2(oacc[0], pah, pal, (kk == 0) ? v00 : v01);
        mfma2(oacc[1], pah, pal, (kk == 0) ? v10 : v11);
      }
      // rotate V regs to chunk ct
      const size_t vo = vb0 + (size_t)ct * 64;
      v00 = ldfrag(VThi + vo);
      v01 = ldfrag(VThi + vo + 32);
      v10 = ldfrag(VThi + vo + (size_t)16 * S);
      v11 = ldfrag(VThi + vo + (size_t)16 * S + 32);
    }
    // ---- stage K chunk ct (from prefetched regs) ----
    *(bf16x8*)&Ksh[tr][kc] = rkh;
    *(bf16x8*)&Ksl[tr][kc] = rkl;
    if (ct < 2) {
      rkh = ldfrag(Khi + gkbase + (size_t)(ct + 1) * 4096);
      rkl = ldfrag(Klo + gkbase + (size_t)(ct + 1) * 4096);
    }
    __syncthreads();   // B: K(ct) visible to all; PV(ct-1) done before any
                       //    wave's QK(ct) overwrites P
    // ---- QK chunk ct: 2 column-quadrant passes per wave ----
    #pragma unroll
    for (int cp = 0; cp < 2; ++cp) {
      const int tcol = nqq + cp * 32;   // 0,16,32,48
      f32x4 d = {0.0f, 0.0f, 0.0f, 0.0f};
      bf16x8 bh0 = *(const bf16x8*)&Ksh[tcol + l15][q8];
      bf16x8 bl0 = *(const bf16x8*)&Ksl[tcol + l15][q8];
      bf16x8 bh1 = *(const bf16x8*)&Ksh[tcol + l15][32 + q8];
      bf16x8 bl1 = *(const bf16x8*)&Ksl[tcol + l15][32 + q8];
      mfma3(d, qh0, ql0, bh0, bl0);
      mfma3(d, qh1, ql1, bh1, bl1);
      const int tl = ct * 64 + tcol + l15;
      #pragma unroll
      for (int r = 0; r < 4; ++r) {
        const int srow = mq + q4 + r;
        const unsigned w = msk[srow][tl >> 5];
        float e = ((w >> (tl & 31)) & 1u) ? __expf(d[r] * 0.125f) : 0.0f;
        unsigned short h16, l16;
        split1(e, h16, l16);
        Pshi[srow][tcol + l15] = h16;
        Pslo[srow][tcol + l15] = l16;
        esum[r] += e;
      }
    }
  }
  // ---- epilogue: final PV (chunk 2) ----
  __syncthreads();
  #pragma unroll
  for (int kk = 0; kk < 64; kk += 32) {
    bf16x8 pah = *(const bf16x8*)&Pshi[mq + l15][kk + q8];
    bf16x8 pal = *(const bf16x8*)&Pslo[mq + l15][kk + q8];
    mfma2(oacc[0], pah, pal, (kk == 0) ? v00 : v01);
    mfma2(oacc[1], pah, pal, (kk == 0) ? v10 : v11);
  }
  // ---- O atomics (independent of rsumf) ----
  #pragma unroll
  for (int dt = 0; dt < 2; ++dt) {
    const int dd = db + dt * 16 + l15;
    #pragma unroll
    for (int r = 0; r < 4; ++r) {
      const int s = s0 + mq + q4 + r;
      atomicAdd(&ATTacc[(size_t)s * E + h * DK + dd], oacc[dt][r]);
    }
  }
  // ---- row sums: single reduction at the end ----
  #pragma unroll
  for (int off = 1; off < 16; off <<= 1) {
    esum[0] += __shfl_xor(esum[0], off);
    esum[1] += __shfl_xor(esum[1], off);
    esum[2] += __shfl_xor(esum[2], off);
    esum[3] += __shfl_xor(esum[3], off);
  }
  if (l15 == 0) {
    atomicAdd(&rsumf[q4 + 0 + mq], esum[0]);
    atomicAdd(&rsumf[q4 + 1 + mq], esum[1]);
    atomicAdd(&rsumf[q4 + 2 + mq], esum[2]);
    atomicAdd(&rsumf[q4 + 3 + mq], esum[3]);
  }
  __syncthreads();
  if (tid < 64) atomicAdd(&Sum[(size_t)h * S + s0 + tid], rsumf[tid]);
}

// ---------------------------------------------------------------------------
// Output projection via MFMA (R1-exact: cooperative normalize+split staging)
// ---------------------------------------------------------------------------
__global__ __launch_bounds__(512) void out_mfma_kernel(
    const float* __restrict__ ATTacc, const float* __restrict__ Sum,
    const unsigned short* __restrict__ WoThi,
    const float* __restrict__ bo, float* __restrict__ out) {
  __shared__ float AccL[16][65];
  __shared__ float ivs[16][8];
  __shared__ __align__(16) unsigned short Ahi[16][520];
  __shared__ __align__(16) unsigned short Alo[16][520];
  const int tid512 = threadIdx.x;
  const int wave8 = tid512 >> 6;
  const int z = wave8 >> 2;
  const int wave = wave8 & 3;
  const int lane = tid512 & 63;
  const int m0 = blockIdx.y * 16;
  const int n0 = blockIdx.x * 64 + wave * 16;
  const int l15 = lane & 15;
  const int q8 = (lane >> 4) << 3;
  const int q4 = (lane >> 4) << 2;
  if (tid512 < 128) {
    const int r = tid512 >> 3, hh = tid512 & 7;
    ivs[r][hh] = 1.0f / Sum[(size_t)hh * S + m0 + r];
  }
  __syncthreads();
  {
    const int row = tid512 >> 5;
    const int kb = (tid512 & 31) << 4;
    const float inv = ivs[row][kb >> 6];
    const float* src = ATTacc + (size_t)(m0 + row) * 512 + kb;
    float4 a0 = *(const float4*)(src);
    float4 a1 = *(const float4*)(src + 4);
    float4 a2 = *(const float4*)(src + 8);
    float4 a3 = *(const float4*)(src + 12);
    float v[16] = {a0.x, a0.y, a0.z, a0.w, a1.x, a1.y, a1.z, a1.w,
                   a2.x, a2.y, a2.z, a2.w, a3.x, a3.y, a3.z, a3.w};
    #pragma unroll
    for (int i = 0; i < 16; ++i) {
      unsigned short hh, ll;
      split1(v[i] * inv, hh, ll);
      Ahi[row][kb + i] = hh;
      Alo[row][kb + i] = ll;
    }
  }
  __syncthreads();
  const size_t brow = (size_t)(n0 + l15) * 512;
  f32x4 acc = {};
  #pragma unroll
  for (int it = 0; it < 8; ++it) {
    const int ko = (z << 8) + (it << 5) + q8;
    bf16x8 ah = *(const bf16x8*)&Ahi[l15][ko];
    bf16x8 al = *(const bf16x8*)&Alo[l15][ko];
    bf16x8 bh = ldfrag(WoThi + brow + ko);
    mfma2(acc, ah, al, bh);
  }
  if (z == 1) {
    #pragma unroll
    for (int r = 0; r < 4; ++r)
      AccL[q4 + r][wave * 16 + l15] = acc[r];
  }
  __syncthreads();
  if (z == 0) {
    const int n = n0 + l15;
    const float bv = bo[n];
    #pragma unroll
    for (int r = 0; r < 4; ++r)
      out[(size_t)(m0 + q4 + r) * 512 + n] =
          acc[r] + AccL[q4 + r][wave * 16 + l15] + bv;
  }
}

// ---------------------------------------------------------------------------
// Launch
// ---------------------------------------------------------------------------
extern "C" void kernel_launch(void* const* d_in, const int* in_sizes, int n_in,
                              void* d_out, int out_size, void* d_ws, size_t ws_size,
                              hipStream_t stream) {
  const float* x    = (const float*)d_in[0];
  const float* Wq   = (const float*)d_in[1];
  const float* bq   = (const float*)d_in[2];
  const float* Wk   = (const float*)d_in[3];
  const float* bk   = (const float*)d_in[4];
  const float* Wv   = (const float*)d_in[5];
  const float* bv   = (const float*)d_in[6];
  const float* Wo   = (const float*)d_in[7];
  const float* bo   = (const float*)d_in[8];
  const float* iqW  = (const float*)d_in[9];
  const float* iqb  = (const float*)d_in[10];
  const float* ikW  = (const float*)d_in[11];
  const float* ikb  = (const float*)d_in[12];
  const float* wpW  = (const float*)d_in[13];
  const float* wpb  = (const float*)d_in[14];

  float* ws = (float*)d_ws;
  float* WI   = ws;                         // S*H fp32
  float* ISC  = WI + S * H;                 // S*S fp32
  unsigned* Mask = (unsigned*)(ISC + S * S);  // S*24
  float* Sum  = (float*)(Mask + S * 24);    // H*S
  float* ATTacc = Sum + H * S;              // S*E fp32 (atomic accumulator)
  unsigned short* u = (unsigned short*)(ATTacc + S * E);
  unsigned short* Xhi  = u;             u += S * E;
  unsigned short* Xlo  = u;             u += S * E;
  unsigned short* Qhi  = u;             u += S * E;
  unsigned short* Qlo  = u;             u += S * E;
  unsigned short* Khi  = u;             u += S * E;
  unsigned short* Klo  = u;             u += S * E;
  unsigned short* VThi = u;             u += S * E;
  unsigned short* QIhi = u;             u += S * E;
  unsigned short* QIlo = u;             u += S * E;
  unsigned short* KIhi = u;             u += S * DK;
  unsigned short* KIlo = u;             u += S * DK;
  unsigned short* WTq_hi = u;           u += E * E;
  unsigned short* WTk_hi = u;           u += E * E;
  unsigned short* WTv_hi = u;           u += E * E;
  unsigned short* WTiq_hi = u;          u += E * E;
  unsigned short* WTik_hi = u;          u += 64 * E;
  unsigned short* WTwp_hi = u;          u += 64 * E;
  unsigned short* WTo_hi = u;           u += E * E;
  unsigned short* WTq_lo = u;           u += E * E;
  unsigned short* WTk_lo = u;           u += E * E;
  unsigned short* WTv_lo = u;           u += E * E;
  unsigned short* WTiq_lo = u;          u += E * E;
  unsigned short* WTik_lo = u;          u += 64 * E;
  unsigned short* WTwp_lo = u;          u += 64 * E;
  unsigned short* WTo_lo = u;           u += E * E;

  PrepTab prep;
  prep.src[0] = x;    prep.hi[0] = Xhi;     prep.lo[0] = Xlo;
  prep.src[1] = Wq;   prep.hi[1] = WTq_hi;  prep.lo[1] = WTq_lo;
  prep.src[2] = Wk;   prep.hi[2] = WTk_hi;  prep.lo[2] = WTk_lo;
  prep.src[3] = Wv;   prep.hi[3] = WTv_hi;  prep.lo[3] = WTv_lo;
  prep.src[4] = iqW;  prep.hi[4] = WTiq_hi; prep.lo[4] = WTiq_lo;
  prep.src[5] = ikW;  prep.hi[5] = WTik_hi; prep.lo[5] = WTik_lo;
  prep.src[6] = wpW;  prep.hi[6] = WTwp_hi; prep.lo[6] = WTwp_lo;
  prep.src[7] = Wo;   prep.hi[7] = WTo_hi;  prep.lo[7] = WTo_lo;

  ProjTab pt;
  pt.whi[0] = WTq_hi;  pt.wlo[0] = WTq_lo;  pt.bias[0] = bq;
  pt.whi[1] = WTk_hi;  pt.wlo[1] = WTk_lo;  pt.bias[1] = bk;
  pt.whi[2] = WTv_hi;  pt.wlo[2] = WTv_lo;  pt.bias[2] = bv;
  pt.whi[3] = WTiq_hi; pt.wlo[3] = WTiq_lo; pt.bias[3] = iqb;
  pt.whi[4] = WTik_hi; pt.wlo[4] = WTik_lo; pt.bias[4] = ikb;
  pt.whi[5] = WTwp_hi; pt.wlo[5] = WTwp_lo; pt.bias[5] = wpb;

  // 1) split x + transpose/split all weight matrices
  prep_kernel<<<dim3(16, 24, 8), dim3(256), 0, stream>>>(prep);
  // 2) projections via MFMA (R1)
  proj_mfma_kernel<<<dim3(34, S / 64), dim3(256), 0, stream>>>(
      Xhi, Xlo, pt, Qhi, Qlo, Khi, Klo, VThi, QIhi, QIlo, KIhi, KIlo, WI);
  // 3) indexer via MFMA (R1)
  indexer_mfma_kernel<<<dim3(S / 64, S / 32), dim3(256), 0, stream>>>(
      QIhi, QIlo, KIhi, KIlo, WI, ISC);
  // 4) top-k per row (radix select, shfl scan; zeroes Sum and ATTacc)
  topk_kernel<<<dim3(S), dim3(256), 0, stream>>>(ISC, Mask, Sum, ATTacc);
  // 5) fused masked attention (K LDS-staged, V in regs, 2 barriers/chunk)
  sattn_kernel<<<dim3(4, S / 64, H), dim3(512), 0, stream>>>(
      Qhi, Qlo, Khi, Klo, VThi, Mask, ATTacc, Sum);
  // 6) output projection (R1)
  out_mfma_kernel<<<dim3(8, 48), dim3(512), 0, stream>>>(
      ATTacc, Sum, WTo_hi, bo, (float*)d_out);
}